// Round 6
// baseline (1162.381 us; speedup 1.0000x reference)
//
#include <hip/hip_runtime.h>
#include <math.h>

#define NL 16
#define HASH_SIZE (1u << 19)
#define HASH_MASK (HASH_SIZE - 1u)
#define P1 2654435761u
#define P2 805459861u
#define PTS_PER_BLOCK 1024
#define THREADS 256

typedef float f2 __attribute__((ext_vector_type(2)));
typedef float f4 __attribute__((ext_vector_type(4)));

struct Res16 { float r[NL]; };

// All 8 corner features of one (point, level) plus trilinear fracs.
// Named fields only (runtime-indexed arrays would spill to scratch).
struct PL {
    f2 f000, f001, f010, f011, f100, f101, f110, f111;
    float wx, wy, wz;
};

// Issue phase: compute hash addresses and ISSUE all 8 gathers. No use of the
// loaded values here -> compiler keeps them in flight (counted vmcnt) while
// the caller issues the next point's gathers.
__device__ __forceinline__ PL enc_issue(const f2* __restrict__ tb, float r,
                                        float px, float py, float pz)
{
    float sx = px * r, sy = py * r, sz = pz * r;
    float fx = floorf(sx), fy = floorf(sy), fz = floorf(sz);
    PL g;
    g.wx = sx - fx; g.wy = sy - fy; g.wz = sz - fz;
    unsigned ix = (unsigned)(int)fx;
    unsigned iy = (unsigned)(int)fy;
    unsigned iz = (unsigned)(int)fz;
    // per-dim hash partials; uint32 wrap matches reference exactly
    unsigned hx0 = ix,      hx1 = ix + 1u;
    unsigned hy0 = iy * P1, hy1 = hy0 + P1;
    unsigned hz0 = iz * P2, hz1 = hz0 + P2;

    g.f000 = tb[(hx0 ^ hy0 ^ hz0) & HASH_MASK];
    g.f001 = tb[(hx0 ^ hy0 ^ hz1) & HASH_MASK];
    g.f010 = tb[(hx0 ^ hy1 ^ hz0) & HASH_MASK];
    g.f011 = tb[(hx0 ^ hy1 ^ hz1) & HASH_MASK];
    g.f100 = tb[(hx1 ^ hy0 ^ hz0) & HASH_MASK];
    g.f101 = tb[(hx1 ^ hy0 ^ hz1) & HASH_MASK];
    g.f110 = tb[(hx1 ^ hy1 ^ hz0) & HASH_MASK];
    g.f111 = tb[(hx1 ^ hy1 ^ hz1) & HASH_MASK];
    return g;
}

__device__ __forceinline__ f2 enc_blend(const PL& g)
{
    float wx = g.wx, wy = g.wy, wz = g.wz;
    float wx0 = 1.0f - wx, wy0 = 1.0f - wy, wz0 = 1.0f - wz;
    float c000 = (wx0 * wy0) * wz0, c001 = (wx0 * wy0) * wz;
    float c010 = (wx0 * wy ) * wz0, c011 = (wx0 * wy ) * wz;
    float c100 = (wx  * wy0) * wz0, c101 = (wx  * wy0) * wz;
    float c110 = (wx  * wy ) * wz0, c111 = (wx  * wy ) * wz;
    float a0 = c000 * g.f000.x + c001 * g.f001.x + c010 * g.f010.x + c011 * g.f011.x
             + c100 * g.f100.x + c101 * g.f101.x + c110 * g.f110.x + c111 * g.f111.x;
    float a1 = c000 * g.f000.y + c001 * g.f001.y + c010 * g.f010.y + c011 * g.f011.y
             + c100 * g.f100.y + c101 * g.f101.y + c110 * g.f110.y + c111 * g.f111.y;
    f2 ret; ret.x = a0; ret.y = a1;
    return ret;
}

__device__ __forceinline__ void clamp3(float& px, float& py, float& pz)
{
    px = fminf(fmaxf(px, 0.0f), 0.999999f);
    py = fminf(fmaxf(py, 0.0f), 0.999999f);
    pz = fminf(fmaxf(pz, 0.0f), 0.999999f);
}

// ---- pass 1: one level per block; level = phase*8 + blockIdx%8 so each XCD
// (round-robin mod 8) sees exactly one 4MB table at a time -> L2-resident
// (proved: FETCH 4.5GB -> 332MB). Round 6: 2 points per iteration, all 16
// gathers issued before the first blend -> ~2x outstanding requests/wave. ----
__global__ __launch_bounds__(THREADS) void hashenc_level_kernel(
    const float* __restrict__ x,
    const float* __restrict__ tables,
    float* __restrict__ ws,          // [NL][N][2] level-major
    int N, int nchunks, Res16 res)
{
    int slot  = blockIdx.x & 7;
    int rest  = blockIdx.x >> 3;
    int chunk = rest % nchunks;
    int phase = rest / nchunks;      // 0: levels 0-7, 1: levels 8-15
    int level = phase * 8 + slot;

    float r = res.r[level];
    const f2* __restrict__ tb =
        reinterpret_cast<const f2*>(tables) + (size_t)level * HASH_SIZE;
    f2* __restrict__ wl =
        reinterpret_cast<f2*>(ws) + (size_t)level * N;

    int base = chunk * PTS_PER_BLOCK + threadIdx.x;
#pragma unroll
    for (int ii = 0; ii < PTS_PER_BLOCK / THREADS; ii += 2) {
        int n0 = base + ii * THREADS;
        int n1 = n0 + THREADS;
        if (n1 < N) {
            // nt x reads: don't let the 24MB x stream evict table lines
            float p0x = __builtin_nontemporal_load(x + 3 * (size_t)n0 + 0);
            float p0y = __builtin_nontemporal_load(x + 3 * (size_t)n0 + 1);
            float p0z = __builtin_nontemporal_load(x + 3 * (size_t)n0 + 2);
            float p1x = __builtin_nontemporal_load(x + 3 * (size_t)n1 + 0);
            float p1y = __builtin_nontemporal_load(x + 3 * (size_t)n1 + 1);
            float p1z = __builtin_nontemporal_load(x + 3 * (size_t)n1 + 2);
            clamp3(p0x, p0y, p0z);
            clamp3(p1x, p1y, p1z);
            PL g0 = enc_issue(tb, r, p0x, p0y, p0z);   // 8 loads in flight
            PL g1 = enc_issue(tb, r, p1x, p1y, p1z);   // +8 more in flight
            f2 a0 = enc_blend(g0);                     // waits only g0's loads
            f2 a1 = enc_blend(g1);
            __builtin_nontemporal_store(a0, wl + n0);
            __builtin_nontemporal_store(a1, wl + n1);
        } else if (n0 < N) {
            float p0x = __builtin_nontemporal_load(x + 3 * (size_t)n0 + 0);
            float p0y = __builtin_nontemporal_load(x + 3 * (size_t)n0 + 1);
            float p0z = __builtin_nontemporal_load(x + 3 * (size_t)n0 + 2);
            clamp3(p0x, p0y, p0z);
            PL g0 = enc_issue(tb, r, p0x, p0y, p0z);
            f2 a0 = enc_blend(g0);
            __builtin_nontemporal_store(a0, wl + n0);
        }
    }
}

// ---- pass 2: 8 lanes cooperate per point; wave reads 16 coalesced 8B
// streams, writes 1KB contiguous (fixed the 4x partial-line stores). ----
__global__ __launch_bounds__(THREADS) void hashenc_transpose_kernel(
    const float* __restrict__ ws, float* __restrict__ out, int N)
{
    int c    = threadIdx.x & 7;      // feature chunk -> levels 2c, 2c+1
    int pid  = threadIdx.x >> 3;     // 0..31
    int base = blockIdx.x * 256;     // 256 points per block
    const f2* __restrict__ w2 = reinterpret_cast<const f2*>(ws);
#pragma unroll
    for (int i = 0; i < 8; ++i) {
        int p = base + i * 32 + pid;
        if (p >= N) return;
        f2 a = __builtin_nontemporal_load(w2 + (size_t)(2 * c)     * N + p);
        f2 b = __builtin_nontemporal_load(w2 + (size_t)(2 * c + 1) * N + p);
        f4 v; v.x = a.x; v.y = a.y; v.z = b.x; v.w = b.y;
        __builtin_nontemporal_store(
            v, reinterpret_cast<f4*>(out + (size_t)p * (2 * NL) + c * 4));
    }
}

// ---- fallback (monolithic) if ws is too small ----
__global__ __launch_bounds__(THREADS) void hashenc_mono_kernel(
    const float* __restrict__ x, const float* __restrict__ tables,
    float* __restrict__ out, int N, Res16 res)
{
    int n = blockIdx.x * THREADS + threadIdx.x;
    if (n >= N) return;
    float px = x[3 * (size_t)n + 0], py = x[3 * (size_t)n + 1], pz = x[3 * (size_t)n + 2];
    clamp3(px, py, pz);
    float acc[2 * NL];
#pragma unroll
    for (int l = 0; l < NL; ++l) {
        const f2* tb = reinterpret_cast<const f2*>(tables) + (size_t)l * HASH_SIZE;
        PL g = enc_issue(tb, res.r[l], px, py, pz);
        f2 a = enc_blend(g);
        acc[2 * l] = a.x; acc[2 * l + 1] = a.y;
    }
    f4* o = reinterpret_cast<f4*>(out + (size_t)n * (2 * NL));
#pragma unroll
    for (int q = 0; q < 8; ++q) {
        f4 v; v.x = acc[4*q]; v.y = acc[4*q+1]; v.z = acc[4*q+2]; v.w = acc[4*q+3];
        o[q] = v;
    }
}

extern "C" void kernel_launch(void* const* d_in, const int* in_sizes, int n_in,
                              void* d_out, int out_size, void* d_ws, size_t ws_size,
                              hipStream_t stream)
{
    const float* x      = (const float*)d_in[0];
    const float* tables = (const float*)d_in[1];
    float* out          = (float*)d_out;
    int N = in_sizes[0] / 3;

    // Replicate numpy's resolutions bit-for-bit with glibc doubles (levels
    // 3/6/9/12/15 sit on exact ceil boundaries -> must compute, not guess).
    Res16 res;
    double b = exp((log(512.0) - log(16.0)) / 15.0);
    for (int i = 0; i < NL; ++i)
        res.r[i] = (float)(int)ceil(16.0 * pow(b, (double)i));

    size_t ws_need = (size_t)NL * (size_t)N * 2 * sizeof(float);
    if (ws_size >= ws_need) {
        int nchunks = (N + PTS_PER_BLOCK - 1) / PTS_PER_BLOCK;
        int gridA = 2 * 8 * nchunks;   // phase-major: levels 0-7 then 8-15
        hipLaunchKernelGGL(hashenc_level_kernel, dim3(gridA), dim3(THREADS), 0, stream,
                           x, tables, (float*)d_ws, N, nchunks, res);
        int gridB = (N + 255) / 256;
        hipLaunchKernelGGL(hashenc_transpose_kernel, dim3(gridB), dim3(THREADS), 0, stream,
                           (const float*)d_ws, out, N);
    } else {
        int grid = (N + THREADS - 1) / THREADS;
        hipLaunchKernelGGL(hashenc_mono_kernel, dim3(grid), dim3(THREADS), 0, stream,
                           x, tables, out, N, res);
    }
}

// Round 7
// 913.021 us; speedup vs baseline: 1.2731x; 1.2731x over previous
//
#include <hip/hip_runtime.h>
#include <math.h>

#define NL 16
#define HASH_SIZE (1u << 19)
#define HASH_MASK (HASH_SIZE - 1u)
#define P1 2654435761u
#define P2 805459861u
#define PTS_PER_BLOCK 1024
#define THREADS 256
#define BX 32              // spatial bins per axis
#define NB (BX * BX * BX)  // 32768 bins

typedef float f2 __attribute__((ext_vector_type(2)));
typedef float f4 __attribute__((ext_vector_type(4)));

struct Res16 { float r[NL]; };

__device__ __forceinline__ void clamp3(float& px, float& py, float& pz)
{
    px = fminf(fmaxf(px, 0.0f), 0.999999f);
    py = fminf(fmaxf(py, 0.0f), 0.999999f);
    pz = fminf(fmaxf(pz, 0.0f), 0.999999f);
}

// ---- per-(point,level): 8 hash gathers + trilinear blend (branchless) ----
__device__ __forceinline__ f2 enc_pl_simple(const f2* __restrict__ tb, float r,
                                            float px, float py, float pz)
{
    float sx = px * r, sy = py * r, sz = pz * r;
    float fx = floorf(sx), fy = floorf(sy), fz = floorf(sz);
    float wx = sx - fx, wy = sy - fy, wz = sz - fz;
    unsigned ix = (unsigned)(int)fx;
    unsigned iy = (unsigned)(int)fy;
    unsigned iz = (unsigned)(int)fz;
    unsigned hx0 = ix,      hx1 = ix + 1u;
    unsigned hy0 = iy * P1, hy1 = hy0 + P1;
    unsigned hz0 = iz * P2, hz1 = hz0 + P2;

    f2 f000 = tb[(hx0 ^ hy0 ^ hz0) & HASH_MASK];
    f2 f001 = tb[(hx0 ^ hy0 ^ hz1) & HASH_MASK];
    f2 f010 = tb[(hx0 ^ hy1 ^ hz0) & HASH_MASK];
    f2 f011 = tb[(hx0 ^ hy1 ^ hz1) & HASH_MASK];
    f2 f100 = tb[(hx1 ^ hy0 ^ hz0) & HASH_MASK];
    f2 f101 = tb[(hx1 ^ hy0 ^ hz1) & HASH_MASK];
    f2 f110 = tb[(hx1 ^ hy1 ^ hz0) & HASH_MASK];
    f2 f111 = tb[(hx1 ^ hy1 ^ hz1) & HASH_MASK];

    float wx0 = 1.0f - wx, wy0 = 1.0f - wy, wz0 = 1.0f - wz;
    float c000 = (wx0 * wy0) * wz0, c001 = (wx0 * wy0) * wz;
    float c010 = (wx0 * wy ) * wz0, c011 = (wx0 * wy ) * wz;
    float c100 = (wx  * wy0) * wz0, c101 = (wx  * wy0) * wz;
    float c110 = (wx  * wy ) * wz0, c111 = (wx  * wy ) * wz;

    float a0 = c000 * f000.x + c001 * f001.x + c010 * f010.x + c011 * f011.x
             + c100 * f100.x + c101 * f101.x + c110 * f110.x + c111 * f111.x;
    float a1 = c000 * f000.y + c001 * f001.y + c010 * f010.y + c011 * f011.y
             + c100 * f100.y + c101 * f101.y + c110 * f110.y + c111 * f111.y;
    f2 ret; ret.x = a0; ret.y = a1;
    return ret;
}

// ---- round-5 merged variant (x-pair f4 merge) for the no-ws fallback ----
__device__ __forceinline__ f2 enc_pl_merged(const f2* __restrict__ tb, float r,
                                            float px, float py, float pz)
{
    float sx = px * r, sy = py * r, sz = pz * r;
    float fx = floorf(sx), fy = floorf(sy), fz = floorf(sz);
    float wx = sx - fx, wy = sy - fy, wz = sz - fz;
    unsigned ix = (unsigned)(int)fx;
    unsigned iy = (unsigned)(int)fy;
    unsigned iz = (unsigned)(int)fz;
    unsigned hy0 = iy * P1, hy1 = hy0 + P1;
    unsigned hz0 = iz * P2, hz1 = hz0 + P2;
    f2 f000, f001, f010, f011, f100, f101, f110, f111;
    if ((ix & 1u) == 0u) {
        const f4* __restrict__ tb4 = reinterpret_cast<const f4*>(tb);
        unsigned g00 = (ix ^ hy0 ^ hz0) & HASH_MASK;
        unsigned g01 = (ix ^ hy0 ^ hz1) & HASH_MASK;
        unsigned g10 = (ix ^ hy1 ^ hz0) & HASH_MASK;
        unsigned g11 = (ix ^ hy1 ^ hz1) & HASH_MASK;
        f4 v00 = tb4[g00 >> 1]; f4 v01 = tb4[g01 >> 1];
        f4 v10 = tb4[g10 >> 1]; f4 v11 = tb4[g11 >> 1];
        f2 lo, hi;
        lo.x = v00.x; lo.y = v00.y; hi.x = v00.z; hi.y = v00.w;
        f000 = (g00 & 1u) ? hi : lo;  f100 = (g00 & 1u) ? lo : hi;
        lo.x = v01.x; lo.y = v01.y; hi.x = v01.z; hi.y = v01.w;
        f001 = (g01 & 1u) ? hi : lo;  f101 = (g01 & 1u) ? lo : hi;
        lo.x = v10.x; lo.y = v10.y; hi.x = v10.z; hi.y = v10.w;
        f010 = (g10 & 1u) ? hi : lo;  f110 = (g10 & 1u) ? lo : hi;
        lo.x = v11.x; lo.y = v11.y; hi.x = v11.z; hi.y = v11.w;
        f011 = (g11 & 1u) ? hi : lo;  f111 = (g11 & 1u) ? lo : hi;
    } else {
        unsigned hx0 = ix, hx1 = ix + 1u;
        f000 = tb[(hx0 ^ hy0 ^ hz0) & HASH_MASK];
        f001 = tb[(hx0 ^ hy0 ^ hz1) & HASH_MASK];
        f010 = tb[(hx0 ^ hy1 ^ hz0) & HASH_MASK];
        f011 = tb[(hx0 ^ hy1 ^ hz1) & HASH_MASK];
        f100 = tb[(hx1 ^ hy0 ^ hz0) & HASH_MASK];
        f101 = tb[(hx1 ^ hy0 ^ hz1) & HASH_MASK];
        f110 = tb[(hx1 ^ hy1 ^ hz0) & HASH_MASK];
        f111 = tb[(hx1 ^ hy1 ^ hz1) & HASH_MASK];
    }
    float wx0 = 1.0f - wx, wy0 = 1.0f - wy, wz0 = 1.0f - wz;
    float c000 = (wx0 * wy0) * wz0, c001 = (wx0 * wy0) * wz;
    float c010 = (wx0 * wy ) * wz0, c011 = (wx0 * wy ) * wz;
    float c100 = (wx  * wy0) * wz0, c101 = (wx  * wy0) * wz;
    float c110 = (wx  * wy ) * wz0, c111 = (wx  * wy ) * wz;
    float a0 = c000 * f000.x + c001 * f001.x + c010 * f010.x + c011 * f011.x
             + c100 * f100.x + c101 * f101.x + c110 * f110.x + c111 * f111.x;
    float a1 = c000 * f000.y + c001 * f001.y + c010 * f010.y + c011 * f011.y
             + c100 * f100.y + c101 * f101.y + c110 * f110.y + c111 * f111.y;
    f2 ret; ret.x = a0; ret.y = a1;
    return ret;
}

// ---- sort stage 0: zero hist + cursor (must re-zero every call) ----
__global__ __launch_bounds__(THREADS) void zero_kernel(int* __restrict__ p, int n)
{
    int i = blockIdx.x * THREADS + threadIdx.x;
    if (i < n) p[i] = 0;
}

// ---- sort stage 1: LDS histogram of 32^3 spatial bins ----
__global__ __launch_bounds__(THREADS) void hist_kernel(
    const float* __restrict__ x, int* __restrict__ hist, int N)
{
    __shared__ int lh[NB];                       // 128 KB LDS
    for (int i = threadIdx.x; i < NB; i += THREADS) lh[i] = 0;
    __syncthreads();
    for (int n = blockIdx.x * THREADS + threadIdx.x; n < N;
         n += gridDim.x * THREADS) {
        float px = x[3 * (size_t)n + 0];
        float py = x[3 * (size_t)n + 1];
        float pz = x[3 * (size_t)n + 2];
        clamp3(px, py, pz);
        int bin = ((int)(pz * BX) * BX + (int)(py * BX)) * BX + (int)(px * BX);
        atomicAdd(&lh[bin], 1);
    }
    __syncthreads();
    for (int i = threadIdx.x; i < NB; i += THREADS)
        if (lh[i]) atomicAdd(&hist[i], lh[i]);
}

// ---- sort stage 2: exclusive scan (single block) -> cursor ----
__global__ __launch_bounds__(THREADS) void scan_kernel(
    const int* __restrict__ hist, int* __restrict__ cursor)
{
    __shared__ int part[THREADS];
    int t = threadIdx.x;
    int s = 0;
    for (int i = 0; i < NB / THREADS; ++i) s += hist[t * (NB / THREADS) + i];
    part[t] = s;
    __syncthreads();
    for (int off = 1; off < THREADS; off <<= 1) {
        int v = (t >= off) ? part[t - off] : 0;
        __syncthreads();
        part[t] += v;
        __syncthreads();
    }
    int run = part[t] - s;                       // exclusive prefix
    for (int i = 0; i < NB / THREADS; ++i) {
        int b = t * (NB / THREADS) + i;
        cursor[b] = run;
        run += hist[b];
    }
}

// ---- sort stage 3: scatter points into bin order (clamped coords + perm) ----
__global__ __launch_bounds__(THREADS) void scatter_kernel(
    const float* __restrict__ x, int* __restrict__ cursor,
    float* __restrict__ sx, int* __restrict__ perm, int N)
{
    int n = blockIdx.x * THREADS + threadIdx.x;
    if (n >= N) return;
    float px = x[3 * (size_t)n + 0];
    float py = x[3 * (size_t)n + 1];
    float pz = x[3 * (size_t)n + 2];
    clamp3(px, py, pz);
    int bin = ((int)(pz * BX) * BX + (int)(py * BX)) * BX + (int)(px * BX);
    int pos = atomicAdd(&cursor[bin], 1);
    f4 v; v.x = px; v.y = py; v.z = pz; v.w = 0.0f;
    *reinterpret_cast<f4*>(sx + (size_t)pos * 4) = v;
    perm[pos] = n;
}

// ---- pass 1: level-per-XCD encode over SORTED points. Wave lanes are now
// spatially adjacent -> coarse/mid levels coalesce to few distinct words
// (TCP broadcast), fine levels share lines along x (hash = ix ^ h(y,z)). ----
__global__ __launch_bounds__(THREADS) void hashenc_level_kernel(
    const float* __restrict__ sx,    // sorted [N][4] (pre-clamped)
    const float* __restrict__ tables,
    float* __restrict__ ws,          // [NL][N][2] level-major, sorted order
    int N, int nchunks, Res16 res)
{
    int slot  = blockIdx.x & 7;
    int rest  = blockIdx.x >> 3;
    int chunk = rest % nchunks;
    int phase = rest / nchunks;      // 0: levels 0-7, 1: levels 8-15
    int level = phase * 8 + slot;

    float r = res.r[level];
    const f2* __restrict__ tb =
        reinterpret_cast<const f2*>(tables) + (size_t)level * HASH_SIZE;
    f2* __restrict__ wl =
        reinterpret_cast<f2*>(ws) + (size_t)level * N;

    int base = chunk * PTS_PER_BLOCK + threadIdx.x;
#pragma unroll
    for (int i = 0; i < PTS_PER_BLOCK / THREADS; ++i) {
        int n = base + i * THREADS;
        if (n >= N) break;
        f4 p = __builtin_nontemporal_load(
            reinterpret_cast<const f4*>(sx + (size_t)n * 4));
        f2 a = enc_pl_simple(tb, r, p.x, p.y, p.z);
        __builtin_nontemporal_store(a, wl + n);
    }
}

// ---- pass 2: transpose + un-permute. 8 lanes per point; reads dense,
// writes one full 128B row per point at out[perm[p]]. ----
__global__ __launch_bounds__(THREADS) void hashenc_transpose_kernel(
    const float* __restrict__ ws, const int* __restrict__ perm,
    float* __restrict__ out, int N)
{
    int c    = threadIdx.x & 7;      // feature chunk -> levels 2c, 2c+1
    int pid  = threadIdx.x >> 3;     // 0..31
    int base = blockIdx.x * 256;     // 256 points per block
    const f2* __restrict__ w2 = reinterpret_cast<const f2*>(ws);
#pragma unroll
    for (int i = 0; i < 8; ++i) {
        int p = base + i * 32 + pid;
        if (p >= N) return;
        f2 a = __builtin_nontemporal_load(w2 + (size_t)(2 * c)     * N + p);
        f2 b = __builtin_nontemporal_load(w2 + (size_t)(2 * c + 1) * N + p);
        int o = perm[p];             // same for all 8 lanes of a point
        f4 v; v.x = a.x; v.y = a.y; v.z = b.x; v.w = b.y;
        __builtin_nontemporal_store(
            v, reinterpret_cast<f4*>(out + (size_t)o * (2 * NL) + c * 4));
    }
}

// ---- fallback: round-5 two-pass (no sort) ----
__global__ __launch_bounds__(THREADS) void hashenc_level_nosort_kernel(
    const float* __restrict__ x, const float* __restrict__ tables,
    float* __restrict__ ws, int N, int nchunks, Res16 res)
{
    int slot  = blockIdx.x & 7;
    int rest  = blockIdx.x >> 3;
    int chunk = rest % nchunks;
    int phase = rest / nchunks;
    int level = phase * 8 + slot;
    float r = res.r[level];
    const f2* __restrict__ tb =
        reinterpret_cast<const f2*>(tables) + (size_t)level * HASH_SIZE;
    f2* __restrict__ wl = reinterpret_cast<f2*>(ws) + (size_t)level * N;
    int base = chunk * PTS_PER_BLOCK + threadIdx.x;
#pragma unroll
    for (int i = 0; i < PTS_PER_BLOCK / THREADS; ++i) {
        int n = base + i * THREADS;
        if (n >= N) break;
        float px = __builtin_nontemporal_load(x + 3 * (size_t)n + 0);
        float py = __builtin_nontemporal_load(x + 3 * (size_t)n + 1);
        float pz = __builtin_nontemporal_load(x + 3 * (size_t)n + 2);
        clamp3(px, py, pz);
        f2 a = enc_pl_merged(tb, r, px, py, pz);
        __builtin_nontemporal_store(a, wl + n);
    }
}

__global__ __launch_bounds__(THREADS) void hashenc_transpose_nosort_kernel(
    const float* __restrict__ ws, float* __restrict__ out, int N)
{
    int c    = threadIdx.x & 7;
    int pid  = threadIdx.x >> 3;
    int base = blockIdx.x * 256;
    const f2* __restrict__ w2 = reinterpret_cast<const f2*>(ws);
#pragma unroll
    for (int i = 0; i < 8; ++i) {
        int p = base + i * 32 + pid;
        if (p >= N) return;
        f2 a = __builtin_nontemporal_load(w2 + (size_t)(2 * c)     * N + p);
        f2 b = __builtin_nontemporal_load(w2 + (size_t)(2 * c + 1) * N + p);
        f4 v; v.x = a.x; v.y = a.y; v.z = b.x; v.w = b.y;
        __builtin_nontemporal_store(
            v, reinterpret_cast<f4*>(out + (size_t)p * (2 * NL) + c * 4));
    }
}

__global__ __launch_bounds__(THREADS) void hashenc_mono_kernel(
    const float* __restrict__ x, const float* __restrict__ tables,
    float* __restrict__ out, int N, Res16 res)
{
    int n = blockIdx.x * THREADS + threadIdx.x;
    if (n >= N) return;
    float px = x[3 * (size_t)n + 0], py = x[3 * (size_t)n + 1], pz = x[3 * (size_t)n + 2];
    clamp3(px, py, pz);
    float acc[2 * NL];
#pragma unroll
    for (int l = 0; l < NL; ++l) {
        const f2* tb = reinterpret_cast<const f2*>(tables) + (size_t)l * HASH_SIZE;
        f2 a = enc_pl_merged(tb, res.r[l], px, py, pz);
        acc[2 * l] = a.x; acc[2 * l + 1] = a.y;
    }
    f4* o = reinterpret_cast<f4*>(out + (size_t)n * (2 * NL));
#pragma unroll
    for (int q = 0; q < 8; ++q) {
        f4 v; v.x = acc[4*q]; v.y = acc[4*q+1]; v.z = acc[4*q+2]; v.w = acc[4*q+3];
        o[q] = v;
    }
}

extern "C" void kernel_launch(void* const* d_in, const int* in_sizes, int n_in,
                              void* d_out, int out_size, void* d_ws, size_t ws_size,
                              hipStream_t stream)
{
    const float* x      = (const float*)d_in[0];
    const float* tables = (const float*)d_in[1];
    float* out          = (float*)d_out;
    int N = in_sizes[0] / 3;

    // Replicate numpy's resolutions bit-for-bit with glibc doubles (levels
    // 3/6/9/12/15 sit on exact ceil boundaries -> must compute, not guess).
    Res16 res;
    double b = exp((log(512.0) - log(16.0)) / 15.0);
    for (int i = 0; i < NL; ++i)
        res.r[i] = (float)(int)ceil(16.0 * pow(b, (double)i));

    // ws layout (floats): [ ws_enc: NL*N*2 | sx: N*4 | perm: N | hist: NB | cursor: NB ]
    size_t enc_f   = (size_t)NL * N * 2;
    size_t need_sort  = (enc_f + (size_t)N * 5 + 2 * NB) * sizeof(float);
    size_t need_plain = enc_f * sizeof(float);

    if (ws_size >= need_sort) {
        float* wse   = (float*)d_ws;
        float* sx    = wse + enc_f;
        int*   perm  = (int*)(sx + (size_t)N * 4);
        int*   hist  = perm + N;
        int*   cursor= hist + NB;

        hipLaunchKernelGGL(zero_kernel, dim3((2 * NB + THREADS - 1) / THREADS),
                           dim3(THREADS), 0, stream, hist, 2 * NB);
        hipLaunchKernelGGL(hist_kernel, dim3(256), dim3(THREADS), 0, stream,
                           x, hist, N);
        hipLaunchKernelGGL(scan_kernel, dim3(1), dim3(THREADS), 0, stream,
                           hist, cursor);
        hipLaunchKernelGGL(scatter_kernel, dim3((N + THREADS - 1) / THREADS),
                           dim3(THREADS), 0, stream, x, cursor, sx, perm, N);

        int nchunks = (N + PTS_PER_BLOCK - 1) / PTS_PER_BLOCK;
        hipLaunchKernelGGL(hashenc_level_kernel, dim3(2 * 8 * nchunks),
                           dim3(THREADS), 0, stream, sx, tables, wse, N, nchunks, res);
        hipLaunchKernelGGL(hashenc_transpose_kernel, dim3((N + 255) / 256),
                           dim3(THREADS), 0, stream, wse, perm, out, N);
    } else if (ws_size >= need_plain) {
        int nchunks = (N + PTS_PER_BLOCK - 1) / PTS_PER_BLOCK;
        hipLaunchKernelGGL(hashenc_level_nosort_kernel, dim3(2 * 8 * nchunks),
                           dim3(THREADS), 0, stream, x, tables, (float*)d_ws,
                           N, nchunks, res);
        hipLaunchKernelGGL(hashenc_transpose_nosort_kernel, dim3((N + 255) / 256),
                           dim3(THREADS), 0, stream, (const float*)d_ws, out, N);
    } else {
        hipLaunchKernelGGL(hashenc_mono_kernel, dim3((N + THREADS - 1) / THREADS),
                           dim3(THREADS), 0, stream, x, tables, out, N, res);
    }
}

// Round 8
// 825.932 us; speedup vs baseline: 1.4074x; 1.1054x over previous
//
#include <hip/hip_runtime.h>
#include <math.h>

#define NL 16
#define HASH_SIZE (1u << 19)
#define HASH_MASK (HASH_SIZE - 1u)
#define P1 2654435761u
#define P2 805459861u
#define PTS_PER_BLOCK 1024
#define THREADS 256
#define BX 32              // spatial bins per axis
#define NB (BX * BX * BX)  // 32768 bins
#define SCAN_BLOCKS (NB / THREADS)   // 128

typedef float f2 __attribute__((ext_vector_type(2)));
typedef float f4 __attribute__((ext_vector_type(4)));

struct Res16 { float r[NL]; };

__device__ __forceinline__ void clamp3(float& px, float& py, float& pz)
{
    px = fminf(fmaxf(px, 0.0f), 0.999999f);
    py = fminf(fmaxf(py, 0.0f), 0.999999f);
    pz = fminf(fmaxf(pz, 0.0f), 0.999999f);
}

// ---- branchless 8x f2 gather + trilinear blend ----
__device__ __forceinline__ f2 enc_pl_simple(const f2* __restrict__ tb, float r,
                                            float px, float py, float pz)
{
    float sx = px * r, sy = py * r, sz = pz * r;
    float fx = floorf(sx), fy = floorf(sy), fz = floorf(sz);
    float wx = sx - fx, wy = sy - fy, wz = sz - fz;
    unsigned ix = (unsigned)(int)fx;
    unsigned iy = (unsigned)(int)fy;
    unsigned iz = (unsigned)(int)fz;
    unsigned hx0 = ix,      hx1 = ix + 1u;
    unsigned hy0 = iy * P1, hy1 = hy0 + P1;
    unsigned hz0 = iz * P2, hz1 = hz0 + P2;

    f2 f000 = tb[(hx0 ^ hy0 ^ hz0) & HASH_MASK];
    f2 f001 = tb[(hx0 ^ hy0 ^ hz1) & HASH_MASK];
    f2 f010 = tb[(hx0 ^ hy1 ^ hz0) & HASH_MASK];
    f2 f011 = tb[(hx0 ^ hy1 ^ hz1) & HASH_MASK];
    f2 f100 = tb[(hx1 ^ hy0 ^ hz0) & HASH_MASK];
    f2 f101 = tb[(hx1 ^ hy0 ^ hz1) & HASH_MASK];
    f2 f110 = tb[(hx1 ^ hy1 ^ hz0) & HASH_MASK];
    f2 f111 = tb[(hx1 ^ hy1 ^ hz1) & HASH_MASK];

    float wx0 = 1.0f - wx, wy0 = 1.0f - wy, wz0 = 1.0f - wz;
    float c000 = (wx0 * wy0) * wz0, c001 = (wx0 * wy0) * wz;
    float c010 = (wx0 * wy ) * wz0, c011 = (wx0 * wy ) * wz;
    float c100 = (wx  * wy0) * wz0, c101 = (wx  * wy0) * wz;
    float c110 = (wx  * wy ) * wz0, c111 = (wx  * wy ) * wz;

    float a0 = c000 * f000.x + c001 * f001.x + c010 * f010.x + c011 * f011.x
             + c100 * f100.x + c101 * f101.x + c110 * f110.x + c111 * f111.x;
    float a1 = c000 * f000.y + c001 * f001.y + c010 * f010.y + c011 * f011.y
             + c100 * f100.y + c101 * f101.y + c110 * f110.y + c111 * f111.y;
    f2 ret; ret.x = a0; ret.y = a1;
    return ret;
}

// ---- x-pair merged variant: even ix -> 4 aligned f4 gathers (proven -10%) ----
__device__ __forceinline__ f2 enc_pl_merged(const f2* __restrict__ tb, float r,
                                            float px, float py, float pz)
{
    float sx = px * r, sy = py * r, sz = pz * r;
    float fx = floorf(sx), fy = floorf(sy), fz = floorf(sz);
    float wx = sx - fx, wy = sy - fy, wz = sz - fz;
    unsigned ix = (unsigned)(int)fx;
    unsigned iy = (unsigned)(int)fy;
    unsigned iz = (unsigned)(int)fz;
    unsigned hy0 = iy * P1, hy1 = hy0 + P1;
    unsigned hz0 = iz * P2, hz1 = hz0 + P2;
    f2 f000, f001, f010, f011, f100, f101, f110, f111;
    if ((ix & 1u) == 0u) {
        const f4* __restrict__ tb4 = reinterpret_cast<const f4*>(tb);
        unsigned g00 = (ix ^ hy0 ^ hz0) & HASH_MASK;
        unsigned g01 = (ix ^ hy0 ^ hz1) & HASH_MASK;
        unsigned g10 = (ix ^ hy1 ^ hz0) & HASH_MASK;
        unsigned g11 = (ix ^ hy1 ^ hz1) & HASH_MASK;
        f4 v00 = tb4[g00 >> 1]; f4 v01 = tb4[g01 >> 1];
        f4 v10 = tb4[g10 >> 1]; f4 v11 = tb4[g11 >> 1];
        f2 lo, hi;
        lo.x = v00.x; lo.y = v00.y; hi.x = v00.z; hi.y = v00.w;
        f000 = (g00 & 1u) ? hi : lo;  f100 = (g00 & 1u) ? lo : hi;
        lo.x = v01.x; lo.y = v01.y; hi.x = v01.z; hi.y = v01.w;
        f001 = (g01 & 1u) ? hi : lo;  f101 = (g01 & 1u) ? lo : hi;
        lo.x = v10.x; lo.y = v10.y; hi.x = v10.z; hi.y = v10.w;
        f010 = (g10 & 1u) ? hi : lo;  f110 = (g10 & 1u) ? lo : hi;
        lo.x = v11.x; lo.y = v11.y; hi.x = v11.z; hi.y = v11.w;
        f011 = (g11 & 1u) ? hi : lo;  f111 = (g11 & 1u) ? lo : hi;
    } else {
        unsigned hx0 = ix, hx1 = ix + 1u;
        f000 = tb[(hx0 ^ hy0 ^ hz0) & HASH_MASK];
        f001 = tb[(hx0 ^ hy0 ^ hz1) & HASH_MASK];
        f010 = tb[(hx0 ^ hy1 ^ hz0) & HASH_MASK];
        f011 = tb[(hx0 ^ hy1 ^ hz1) & HASH_MASK];
        f100 = tb[(hx1 ^ hy0 ^ hz0) & HASH_MASK];
        f101 = tb[(hx1 ^ hy0 ^ hz1) & HASH_MASK];
        f110 = tb[(hx1 ^ hy1 ^ hz0) & HASH_MASK];
        f111 = tb[(hx1 ^ hy1 ^ hz1) & HASH_MASK];
    }
    float wx0 = 1.0f - wx, wy0 = 1.0f - wy, wz0 = 1.0f - wz;
    float c000 = (wx0 * wy0) * wz0, c001 = (wx0 * wy0) * wz;
    float c010 = (wx0 * wy ) * wz0, c011 = (wx0 * wy ) * wz;
    float c100 = (wx  * wy0) * wz0, c101 = (wx  * wy0) * wz;
    float c110 = (wx  * wy ) * wz0, c111 = (wx  * wy ) * wz;
    float a0 = c000 * f000.x + c001 * f001.x + c010 * f010.x + c011 * f011.x
             + c100 * f100.x + c101 * f101.x + c110 * f110.x + c111 * f111.x;
    float a1 = c000 * f000.y + c001 * f001.y + c010 * f010.y + c011 * f011.y
             + c100 * f100.y + c101 * f101.y + c110 * f110.y + c111 * f111.y;
    f2 ret; ret.x = a0; ret.y = a1;
    return ret;
}

// ================= sort front-end =================
__global__ __launch_bounds__(THREADS) void hist_kernel(
    const float* __restrict__ x, int* __restrict__ hist, int N)
{
    __shared__ int lh[NB];                       // 128 KB LDS
    for (int i = threadIdx.x; i < NB; i += THREADS) lh[i] = 0;
    __syncthreads();
    for (int n = blockIdx.x * THREADS + threadIdx.x; n < N;
         n += gridDim.x * THREADS) {
        float px = x[3 * (size_t)n + 0];
        float py = x[3 * (size_t)n + 1];
        float pz = x[3 * (size_t)n + 2];
        clamp3(px, py, pz);
        int bin = ((int)(pz * BX) * BX + (int)(py * BX)) * BX + (int)(px * BX);
        atomicAdd(&lh[bin], 1);
    }
    __syncthreads();
    for (int i = threadIdx.x; i < NB; i += THREADS)
        if (lh[i]) atomicAdd(&hist[i], lh[i]);
}

// parallel scan, 3 stages (replaces the single-block serial scan: one CU
// scanning 32K bins while 255 CUs idled)
__global__ __launch_bounds__(THREADS) void scan1_kernel(
    const int* __restrict__ hist, int* __restrict__ bsum)
{
    __shared__ int sm[THREADS];
    int t = threadIdx.x;
    sm[t] = hist[blockIdx.x * THREADS + t];
    __syncthreads();
    for (int off = THREADS / 2; off > 0; off >>= 1) {
        if (t < off) sm[t] += sm[t + off];
        __syncthreads();
    }
    if (t == 0) bsum[blockIdx.x] = sm[0];
}

__global__ __launch_bounds__(SCAN_BLOCKS) void scan2_kernel(
    const int* __restrict__ bsum, int* __restrict__ bpre)
{
    __shared__ int sm[SCAN_BLOCKS];
    int t = threadIdx.x;
    int v = bsum[t];
    sm[t] = v;
    __syncthreads();
    for (int off = 1; off < SCAN_BLOCKS; off <<= 1) {
        int u = (t >= off) ? sm[t - off] : 0;
        __syncthreads();
        sm[t] += u;
        __syncthreads();
    }
    bpre[t] = sm[t] - v;   // exclusive
}

__global__ __launch_bounds__(THREADS) void scan3_kernel(
    const int* __restrict__ hist, const int* __restrict__ bpre,
    int* __restrict__ cursor)
{
    __shared__ int sm[THREADS];
    int t = threadIdx.x;
    int v = hist[blockIdx.x * THREADS + t];
    sm[t] = v;
    __syncthreads();
    for (int off = 1; off < THREADS; off <<= 1) {
        int u = (t >= off) ? sm[t - off] : 0;
        __syncthreads();
        sm[t] += u;
        __syncthreads();
    }
    cursor[blockIdx.x * THREADS + t] = bpre[blockIdx.x] + sm[t] - v;
}

__global__ __launch_bounds__(THREADS) void scatter_kernel(
    const float* __restrict__ x, int* __restrict__ cursor,
    float* __restrict__ sx, int* __restrict__ perm, int N)
{
    int n = blockIdx.x * THREADS + threadIdx.x;
    if (n >= N) return;
    float px = x[3 * (size_t)n + 0];
    float py = x[3 * (size_t)n + 1];
    float pz = x[3 * (size_t)n + 2];
    clamp3(px, py, pz);
    int bin = ((int)(pz * BX) * BX + (int)(py * BX)) * BX + (int)(px * BX);
    int pos = atomicAdd(&cursor[bin], 1);
    f4 v; v.x = px; v.y = py; v.z = pz; v.w = 0.0f;
    *reinterpret_cast<f4*>(sx + (size_t)pos * 4) = v;
    perm[pos] = n;
}

// ================= encode =================
// coarse levels 0-7 in ONE dispatch, level-per-XCD slot mapping (cheap,
// broadcast-dominated after the sort; small tables stay L2-resident)
__global__ __launch_bounds__(THREADS) void hashenc_coarse_kernel(
    const float* __restrict__ sx, const float* __restrict__ tables,
    float* __restrict__ ws, int N, int nchunks, Res16 res)
{
    int level = blockIdx.x & 7;
    int chunk = blockIdx.x >> 3;
    float r = res.r[level];
    const f2* __restrict__ tb =
        reinterpret_cast<const f2*>(tables) + (size_t)level * HASH_SIZE;
    f2* __restrict__ wl = reinterpret_cast<f2*>(ws) + (size_t)level * N;
    int base = chunk * PTS_PER_BLOCK + threadIdx.x;
#pragma unroll
    for (int i = 0; i < PTS_PER_BLOCK / THREADS; ++i) {
        int n = base + i * THREADS;
        if (n >= N) break;
        f4 p = __builtin_nontemporal_load(
            reinterpret_cast<const f4*>(sx + (size_t)n * 4));
        f2 a = enc_pl_simple(tb, r, p.x, p.y, p.z);
        __builtin_nontemporal_store(a, wl + n);
    }
}

// one FINE level per dispatch: full GPU, uniform block cost (no imbalance),
// table replicated read-only across all 8 per-XCD L2s. x-pair merge cuts
// lane requests 8->6 average.
__global__ __launch_bounds__(THREADS) void hashenc_fine_kernel(
    const float* __restrict__ sx, const float* __restrict__ tb_f,
    float* __restrict__ wl_f, int N, float r)
{
    const f2* __restrict__ tb = reinterpret_cast<const f2*>(tb_f);
    f2* __restrict__ wl = reinterpret_cast<f2*>(wl_f);
    int base = blockIdx.x * PTS_PER_BLOCK + threadIdx.x;
#pragma unroll
    for (int i = 0; i < PTS_PER_BLOCK / THREADS; ++i) {
        int n = base + i * THREADS;
        if (n >= N) break;
        f4 p = __builtin_nontemporal_load(
            reinterpret_cast<const f4*>(sx + (size_t)n * 4));
        f2 a = enc_pl_merged(tb, r, p.x, p.y, p.z);
        __builtin_nontemporal_store(a, wl + n);
    }
}

// ---- transpose + un-permute: 8 lanes per point; dense reads, one full
// 128B row per point scattered to out[perm[p]] (full lines, no partials) ----
__global__ __launch_bounds__(THREADS) void hashenc_transpose_kernel(
    const float* __restrict__ ws, const int* __restrict__ perm,
    float* __restrict__ out, int N)
{
    int c    = threadIdx.x & 7;
    int pid  = threadIdx.x >> 3;
    int base = blockIdx.x * 256;
    const f2* __restrict__ w2 = reinterpret_cast<const f2*>(ws);
#pragma unroll
    for (int i = 0; i < 8; ++i) {
        int p = base + i * 32 + pid;
        if (p >= N) return;
        f2 a = __builtin_nontemporal_load(w2 + (size_t)(2 * c)     * N + p);
        f2 b = __builtin_nontemporal_load(w2 + (size_t)(2 * c + 1) * N + p);
        int o = perm[p];
        f4 v; v.x = a.x; v.y = a.y; v.z = b.x; v.w = b.y;
        __builtin_nontemporal_store(
            v, reinterpret_cast<f4*>(out + (size_t)o * (2 * NL) + c * 4));
    }
}

// ================= fallbacks =================
__global__ __launch_bounds__(THREADS) void hashenc_level_nosort_kernel(
    const float* __restrict__ x, const float* __restrict__ tables,
    float* __restrict__ ws, int N, int nchunks, Res16 res)
{
    int slot  = blockIdx.x & 7;
    int rest  = blockIdx.x >> 3;
    int chunk = rest % nchunks;
    int phase = rest / nchunks;
    int level = phase * 8 + slot;
    float r = res.r[level];
    const f2* __restrict__ tb =
        reinterpret_cast<const f2*>(tables) + (size_t)level * HASH_SIZE;
    f2* __restrict__ wl = reinterpret_cast<f2*>(ws) + (size_t)level * N;
    int base = chunk * PTS_PER_BLOCK + threadIdx.x;
#pragma unroll
    for (int i = 0; i < PTS_PER_BLOCK / THREADS; ++i) {
        int n = base + i * THREADS;
        if (n >= N) break;
        float px = __builtin_nontemporal_load(x + 3 * (size_t)n + 0);
        float py = __builtin_nontemporal_load(x + 3 * (size_t)n + 1);
        float pz = __builtin_nontemporal_load(x + 3 * (size_t)n + 2);
        clamp3(px, py, pz);
        f2 a = enc_pl_merged(tb, r, px, py, pz);
        __builtin_nontemporal_store(a, wl + n);
    }
}

__global__ __launch_bounds__(THREADS) void hashenc_transpose_nosort_kernel(
    const float* __restrict__ ws, float* __restrict__ out, int N)
{
    int c    = threadIdx.x & 7;
    int pid  = threadIdx.x >> 3;
    int base = blockIdx.x * 256;
    const f2* __restrict__ w2 = reinterpret_cast<const f2*>(ws);
#pragma unroll
    for (int i = 0; i < 8; ++i) {
        int p = base + i * 32 + pid;
        if (p >= N) return;
        f2 a = __builtin_nontemporal_load(w2 + (size_t)(2 * c)     * N + p);
        f2 b = __builtin_nontemporal_load(w2 + (size_t)(2 * c + 1) * N + p);
        f4 v; v.x = a.x; v.y = a.y; v.z = b.x; v.w = b.y;
        __builtin_nontemporal_store(
            v, reinterpret_cast<f4*>(out + (size_t)p * (2 * NL) + c * 4));
    }
}

__global__ __launch_bounds__(THREADS) void hashenc_mono_kernel(
    const float* __restrict__ x, const float* __restrict__ tables,
    float* __restrict__ out, int N, Res16 res)
{
    int n = blockIdx.x * THREADS + threadIdx.x;
    if (n >= N) return;
    float px = x[3 * (size_t)n + 0], py = x[3 * (size_t)n + 1], pz = x[3 * (size_t)n + 2];
    clamp3(px, py, pz);
    float acc[2 * NL];
#pragma unroll
    for (int l = 0; l < NL; ++l) {
        const f2* tb = reinterpret_cast<const f2*>(tables) + (size_t)l * HASH_SIZE;
        f2 a = enc_pl_merged(tb, res.r[l], px, py, pz);
        acc[2 * l] = a.x; acc[2 * l + 1] = a.y;
    }
    f4* o = reinterpret_cast<f4*>(out + (size_t)n * (2 * NL));
#pragma unroll
    for (int q = 0; q < 8; ++q) {
        f4 v; v.x = acc[4*q]; v.y = acc[4*q+1]; v.z = acc[4*q+2]; v.w = acc[4*q+3];
        o[q] = v;
    }
}

extern "C" void kernel_launch(void* const* d_in, const int* in_sizes, int n_in,
                              void* d_out, int out_size, void* d_ws, size_t ws_size,
                              hipStream_t stream)
{
    const float* x      = (const float*)d_in[0];
    const float* tables = (const float*)d_in[1];
    float* out          = (float*)d_out;
    int N = in_sizes[0] / 3;

    // Replicate numpy's resolutions bit-for-bit with glibc doubles (levels
    // 3/6/9/12/15 sit on exact ceil boundaries -> must compute, not guess).
    Res16 res;
    double b = exp((log(512.0) - log(16.0)) / 15.0);
    for (int i = 0; i < NL; ++i)
        res.r[i] = (float)(int)ceil(16.0 * pow(b, (double)i));

    // ws floats: [ enc: NL*N*2 | sx: N*4 | perm: N | hist: NB | cursor: NB | bsum+bpre: 2*SCAN_BLOCKS ]
    size_t enc_f      = (size_t)NL * N * 2;
    size_t need_sort  = (enc_f + (size_t)N * 5 + 2 * NB + 2 * SCAN_BLOCKS) * sizeof(float);
    size_t need_plain = enc_f * sizeof(float);

    if (ws_size >= need_sort) {
        float* wse    = (float*)d_ws;
        float* sx     = wse + enc_f;
        int*   perm   = (int*)(sx + (size_t)N * 4);
        int*   hist   = perm + N;
        int*   cursor = hist + NB;
        int*   bsum   = cursor + NB;
        int*   bpre   = bsum + SCAN_BLOCKS;

        hipMemsetAsync(hist, 0, NB * sizeof(int), stream);
        hipLaunchKernelGGL(hist_kernel, dim3(256), dim3(THREADS), 0, stream,
                           x, hist, N);
        hipLaunchKernelGGL(scan1_kernel, dim3(SCAN_BLOCKS), dim3(THREADS), 0, stream,
                           hist, bsum);
        hipLaunchKernelGGL(scan2_kernel, dim3(1), dim3(SCAN_BLOCKS), 0, stream,
                           bsum, bpre);
        hipLaunchKernelGGL(scan3_kernel, dim3(SCAN_BLOCKS), dim3(THREADS), 0, stream,
                           hist, bpre, cursor);
        hipLaunchKernelGGL(scatter_kernel, dim3((N + THREADS - 1) / THREADS),
                           dim3(THREADS), 0, stream, x, cursor, sx, perm, N);

        int nchunks = (N + PTS_PER_BLOCK - 1) / PTS_PER_BLOCK;
        hipLaunchKernelGGL(hashenc_coarse_kernel, dim3(8 * nchunks),
                           dim3(THREADS), 0, stream, sx, tables, wse, N, nchunks, res);
        for (int l = 8; l < NL; ++l) {
            hipLaunchKernelGGL(hashenc_fine_kernel, dim3(nchunks), dim3(THREADS),
                               0, stream,
                               sx,
                               (const float*)(tables + (size_t)l * HASH_SIZE * 2),
                               wse + (size_t)l * N * 2,
                               N, res.r[l]);
        }
        hipLaunchKernelGGL(hashenc_transpose_kernel, dim3((N + 255) / 256),
                           dim3(THREADS), 0, stream, wse, perm, out, N);
    } else if (ws_size >= need_plain) {
        int nchunks = (N + PTS_PER_BLOCK - 1) / PTS_PER_BLOCK;
        hipLaunchKernelGGL(hashenc_level_nosort_kernel, dim3(2 * 8 * nchunks),
                           dim3(THREADS), 0, stream, x, tables, (float*)d_ws,
                           N, nchunks, res);
        hipLaunchKernelGGL(hashenc_transpose_nosort_kernel, dim3((N + 255) / 256),
                           dim3(THREADS), 0, stream, (const float*)d_ws, out, N);
    } else {
        hipLaunchKernelGGL(hashenc_mono_kernel, dim3((N + THREADS - 1) / THREADS),
                           dim3(THREADS), 0, stream, x, tables, out, N, res);
    }
}

// Round 9
// 670.979 us; speedup vs baseline: 1.7324x; 1.2309x over previous
//
#include <hip/hip_runtime.h>
#include <math.h>

#define NL 16
#define NFINE 8            // levels 8-15 staged in ws
#define HASH_SIZE (1u << 19)
#define HASH_MASK (HASH_SIZE - 1u)
#define P1 2654435761u
#define P2 805459861u
#define PTS_PER_BLOCK 1024
#define THREADS 256
#define BX 32              // spatial bins per axis
#define NB (BX * BX * BX)  // 32768 bins
#define SCAN_BLOCKS (NB / THREADS)   // 128

typedef float f2 __attribute__((ext_vector_type(2)));
typedef float f4 __attribute__((ext_vector_type(4)));

struct Res16 { float r[NL]; };

__device__ __forceinline__ void clamp3(float& px, float& py, float& pz)
{
    px = fminf(fmaxf(px, 0.0f), 0.999999f);
    py = fminf(fmaxf(py, 0.0f), 0.999999f);
    pz = fminf(fmaxf(pz, 0.0f), 0.999999f);
}

// ---- branchless 8x f2 gather + trilinear blend ----
__device__ __forceinline__ f2 enc_pl_simple(const f2* __restrict__ tb, float r,
                                            float px, float py, float pz)
{
    float sx = px * r, sy = py * r, sz = pz * r;
    float fx = floorf(sx), fy = floorf(sy), fz = floorf(sz);
    float wx = sx - fx, wy = sy - fy, wz = sz - fz;
    unsigned ix = (unsigned)(int)fx;
    unsigned iy = (unsigned)(int)fy;
    unsigned iz = (unsigned)(int)fz;
    unsigned hx0 = ix,      hx1 = ix + 1u;
    unsigned hy0 = iy * P1, hy1 = hy0 + P1;
    unsigned hz0 = iz * P2, hz1 = hz0 + P2;

    f2 f000 = tb[(hx0 ^ hy0 ^ hz0) & HASH_MASK];
    f2 f001 = tb[(hx0 ^ hy0 ^ hz1) & HASH_MASK];
    f2 f010 = tb[(hx0 ^ hy1 ^ hz0) & HASH_MASK];
    f2 f011 = tb[(hx0 ^ hy1 ^ hz1) & HASH_MASK];
    f2 f100 = tb[(hx1 ^ hy0 ^ hz0) & HASH_MASK];
    f2 f101 = tb[(hx1 ^ hy0 ^ hz1) & HASH_MASK];
    f2 f110 = tb[(hx1 ^ hy1 ^ hz0) & HASH_MASK];
    f2 f111 = tb[(hx1 ^ hy1 ^ hz1) & HASH_MASK];

    float wx0 = 1.0f - wx, wy0 = 1.0f - wy, wz0 = 1.0f - wz;
    float c000 = (wx0 * wy0) * wz0, c001 = (wx0 * wy0) * wz;
    float c010 = (wx0 * wy ) * wz0, c011 = (wx0 * wy ) * wz;
    float c100 = (wx  * wy0) * wz0, c101 = (wx  * wy0) * wz;
    float c110 = (wx  * wy ) * wz0, c111 = (wx  * wy ) * wz;

    float a0 = c000 * f000.x + c001 * f001.x + c010 * f010.x + c011 * f011.x
             + c100 * f100.x + c101 * f101.x + c110 * f110.x + c111 * f111.x;
    float a1 = c000 * f000.y + c001 * f001.y + c010 * f010.y + c011 * f011.y
             + c100 * f100.y + c101 * f101.y + c110 * f110.y + c111 * f111.y;
    f2 ret; ret.x = a0; ret.y = a1;
    return ret;
}

// ---- x-pair merged variant: even ix -> 4 aligned f4 gathers (proven win) ----
__device__ __forceinline__ f2 enc_pl_merged(const f2* __restrict__ tb, float r,
                                            float px, float py, float pz)
{
    float sx = px * r, sy = py * r, sz = pz * r;
    float fx = floorf(sx), fy = floorf(sy), fz = floorf(sz);
    float wx = sx - fx, wy = sy - fy, wz = sz - fz;
    unsigned ix = (unsigned)(int)fx;
    unsigned iy = (unsigned)(int)fy;
    unsigned iz = (unsigned)(int)fz;
    unsigned hy0 = iy * P1, hy1 = hy0 + P1;
    unsigned hz0 = iz * P2, hz1 = hz0 + P2;
    f2 f000, f001, f010, f011, f100, f101, f110, f111;
    if ((ix & 1u) == 0u) {
        const f4* __restrict__ tb4 = reinterpret_cast<const f4*>(tb);
        unsigned g00 = (ix ^ hy0 ^ hz0) & HASH_MASK;
        unsigned g01 = (ix ^ hy0 ^ hz1) & HASH_MASK;
        unsigned g10 = (ix ^ hy1 ^ hz0) & HASH_MASK;
        unsigned g11 = (ix ^ hy1 ^ hz1) & HASH_MASK;
        f4 v00 = tb4[g00 >> 1]; f4 v01 = tb4[g01 >> 1];
        f4 v10 = tb4[g10 >> 1]; f4 v11 = tb4[g11 >> 1];
        f2 lo, hi;
        lo.x = v00.x; lo.y = v00.y; hi.x = v00.z; hi.y = v00.w;
        f000 = (g00 & 1u) ? hi : lo;  f100 = (g00 & 1u) ? lo : hi;
        lo.x = v01.x; lo.y = v01.y; hi.x = v01.z; hi.y = v01.w;
        f001 = (g01 & 1u) ? hi : lo;  f101 = (g01 & 1u) ? lo : hi;
        lo.x = v10.x; lo.y = v10.y; hi.x = v10.z; hi.y = v10.w;
        f010 = (g10 & 1u) ? hi : lo;  f110 = (g10 & 1u) ? lo : hi;
        lo.x = v11.x; lo.y = v11.y; hi.x = v11.z; hi.y = v11.w;
        f011 = (g11 & 1u) ? hi : lo;  f111 = (g11 & 1u) ? lo : hi;
    } else {
        unsigned hx0 = ix, hx1 = ix + 1u;
        f000 = tb[(hx0 ^ hy0 ^ hz0) & HASH_MASK];
        f001 = tb[(hx0 ^ hy0 ^ hz1) & HASH_MASK];
        f010 = tb[(hx0 ^ hy1 ^ hz0) & HASH_MASK];
        f011 = tb[(hx0 ^ hy1 ^ hz1) & HASH_MASK];
        f100 = tb[(hx1 ^ hy0 ^ hz0) & HASH_MASK];
        f101 = tb[(hx1 ^ hy0 ^ hz1) & HASH_MASK];
        f110 = tb[(hx1 ^ hy1 ^ hz0) & HASH_MASK];
        f111 = tb[(hx1 ^ hy1 ^ hz1) & HASH_MASK];
    }
    float wx0 = 1.0f - wx, wy0 = 1.0f - wy, wz0 = 1.0f - wz;
    float c000 = (wx0 * wy0) * wz0, c001 = (wx0 * wy0) * wz;
    float c010 = (wx0 * wy ) * wz0, c011 = (wx0 * wy ) * wz;
    float c100 = (wx  * wy0) * wz0, c101 = (wx  * wy0) * wz;
    float c110 = (wx  * wy ) * wz0, c111 = (wx  * wy ) * wz;
    float a0 = c000 * f000.x + c001 * f001.x + c010 * f010.x + c011 * f011.x
             + c100 * f100.x + c101 * f101.x + c110 * f110.x + c111 * f111.x;
    float a1 = c000 * f000.y + c001 * f001.y + c010 * f010.y + c011 * f011.y
             + c100 * f100.y + c101 * f101.y + c110 * f110.y + c111 * f111.y;
    f2 ret; ret.x = a0; ret.y = a1;
    return ret;
}

// ================= sort front-end =================
__global__ __launch_bounds__(THREADS) void hist_kernel(
    const float* __restrict__ x, int* __restrict__ hist, int N)
{
    __shared__ int lh[NB];                       // 128 KB LDS
    for (int i = threadIdx.x; i < NB; i += THREADS) lh[i] = 0;
    __syncthreads();
    for (int n = blockIdx.x * THREADS + threadIdx.x; n < N;
         n += gridDim.x * THREADS) {
        float px = __builtin_nontemporal_load(x + 3 * (size_t)n + 0);
        float py = __builtin_nontemporal_load(x + 3 * (size_t)n + 1);
        float pz = __builtin_nontemporal_load(x + 3 * (size_t)n + 2);
        clamp3(px, py, pz);
        int bin = ((int)(pz * BX) * BX + (int)(py * BX)) * BX + (int)(px * BX);
        atomicAdd(&lh[bin], 1);
    }
    __syncthreads();
    for (int i = threadIdx.x; i < NB; i += THREADS)
        if (lh[i]) atomicAdd(&hist[i], lh[i]);
}

__global__ __launch_bounds__(THREADS) void scan1_kernel(
    const int* __restrict__ hist, int* __restrict__ bsum)
{
    __shared__ int sm[THREADS];
    int t = threadIdx.x;
    sm[t] = hist[blockIdx.x * THREADS + t];
    __syncthreads();
    for (int off = THREADS / 2; off > 0; off >>= 1) {
        if (t < off) sm[t] += sm[t + off];
        __syncthreads();
    }
    if (t == 0) bsum[blockIdx.x] = sm[0];
}

__global__ __launch_bounds__(SCAN_BLOCKS) void scan2_kernel(
    const int* __restrict__ bsum, int* __restrict__ bpre)
{
    __shared__ int sm[SCAN_BLOCKS];
    int t = threadIdx.x;
    int v = bsum[t];
    sm[t] = v;
    __syncthreads();
    for (int off = 1; off < SCAN_BLOCKS; off <<= 1) {
        int u = (t >= off) ? sm[t - off] : 0;
        __syncthreads();
        sm[t] += u;
        __syncthreads();
    }
    bpre[t] = sm[t] - v;   // exclusive
}

__global__ __launch_bounds__(THREADS) void scan3_kernel(
    const int* __restrict__ hist, const int* __restrict__ bpre,
    int* __restrict__ cursor)
{
    __shared__ int sm[THREADS];
    int t = threadIdx.x;
    int v = hist[blockIdx.x * THREADS + t];
    sm[t] = v;
    __syncthreads();
    for (int off = 1; off < THREADS; off <<= 1) {
        int u = (t >= off) ? sm[t - off] : 0;
        __syncthreads();
        sm[t] += u;
        __syncthreads();
    }
    cursor[blockIdx.x * THREADS + t] = bpre[blockIdx.x] + sm[t] - v;
}

__global__ __launch_bounds__(THREADS) void scatter_kernel(
    const float* __restrict__ x, int* __restrict__ cursor,
    float* __restrict__ sx, int* __restrict__ perm, int N)
{
    int n = blockIdx.x * THREADS + threadIdx.x;
    if (n >= N) return;
    float px = __builtin_nontemporal_load(x + 3 * (size_t)n + 0);
    float py = __builtin_nontemporal_load(x + 3 * (size_t)n + 1);
    float pz = __builtin_nontemporal_load(x + 3 * (size_t)n + 2);
    clamp3(px, py, pz);
    int bin = ((int)(pz * BX) * BX + (int)(py * BX)) * BX + (int)(px * BX);
    int pos = atomicAdd(&cursor[bin], 1);
    f4 v; v.x = px; v.y = py; v.z = pz; v.w = 0.0f;
    *reinterpret_cast<f4*>(sx + (size_t)pos * 4) = v;  // plain: sx re-read a lot
    perm[pos] = n;
}

// ================= encode =================
// one FINE level (8-15) per dispatch: full GPU, uniform block cost, table
// replicated read-only in all 8 per-XCD L2s. sx loads PLAIN (L3-resident).
__global__ __launch_bounds__(THREADS) void hashenc_fine_kernel(
    const float* __restrict__ sx, const float* __restrict__ tb_f,
    float* __restrict__ wl_f, int N, float r)
{
    const f2* __restrict__ tb = reinterpret_cast<const f2*>(tb_f);
    f2* __restrict__ wl = reinterpret_cast<f2*>(wl_f);
    int base = blockIdx.x * PTS_PER_BLOCK + threadIdx.x;
#pragma unroll
    for (int i = 0; i < PTS_PER_BLOCK / THREADS; ++i) {
        int n = base + i * THREADS;
        if (n >= N) break;
        f4 p = *reinterpret_cast<const f4*>(sx + (size_t)n * 4);
        f2 a = enc_pl_merged(tb, r, p.x, p.y, p.z);
        wl[n] = a;    // plain store: let L3 keep ws for the transpose read
    }
}

// ---- fused transpose: coarse levels computed IN-PLACE, fine read from ws.
// 8 lanes per point; lane c computes coarse level c (8 gathers, full wave),
// 4 shfls redistribute levels 2c,2c+1 to chunk lanes c<4; lanes c>=4 read
// fine ws. One f4 store per lane -> full 128B output rows at out[perm[p]].
// Kills the coarse dispatch + its 256MB ws round-trip + 7x sx re-reads. ----
__global__ __launch_bounds__(THREADS) void hashenc_transpose_fused_kernel(
    const float* __restrict__ ws,     // fine-only: [8][N][2]
    const float* __restrict__ sx,
    const int* __restrict__ perm,
    const float* __restrict__ tables,
    float* __restrict__ out, int N, Res16 res)
{
    int c    = threadIdx.x & 7;
    int pid  = threadIdx.x >> 3;
    int lane = threadIdx.x & 63;
    int base = blockIdx.x * 256;
    const f2* __restrict__ w2 = reinterpret_cast<const f2*>(ws);
    const f2* __restrict__ tbc =
        reinterpret_cast<const f2*>(tables) + (size_t)c * HASH_SIZE;
    float rc = res.r[c];
    int srcA = (lane & ~7) | ((2 * c) & 7);   // lane holding level 2c (c<4)
    int srcB = srcA + 1;
#pragma unroll
    for (int i = 0; i < 8; ++i) {
        int p  = base + i * 32 + pid;
        int pc = p < N ? p : N - 1;           // clamp so shfl stays uniform
        f4 pt = *reinterpret_cast<const f4*>(sx + (size_t)pc * 4); // broadcast
        f2 mine = enc_pl_simple(tbc, rc, pt.x, pt.y, pt.z);
        float Ax = __shfl(mine.x, srcA, 64);
        float Ay = __shfl(mine.y, srcA, 64);
        float Bx = __shfl(mine.x, srcB, 64);
        float By = __shfl(mine.y, srcB, 64);
        f4 v;
        if (c < 4) {
            v.x = Ax; v.y = Ay; v.z = Bx; v.w = By;
        } else {
            f2 a = w2[(size_t)(2 * c - 8) * N + pc];
            f2 b = w2[(size_t)(2 * c - 7) * N + pc];
            v.x = a.x; v.y = a.y; v.z = b.x; v.w = b.y;
        }
        if (p < N) {
            int o = perm[p];
            __builtin_nontemporal_store(
                v, reinterpret_cast<f4*>(out + (size_t)o * (2 * NL) + c * 4));
        }
    }
}

// ================= fallbacks (unchanged structure) =================
__global__ __launch_bounds__(THREADS) void hashenc_level_nosort_kernel(
    const float* __restrict__ x, const float* __restrict__ tables,
    float* __restrict__ ws, int N, int nchunks, Res16 res)
{
    int slot  = blockIdx.x & 7;
    int rest  = blockIdx.x >> 3;
    int chunk = rest % nchunks;
    int phase = rest / nchunks;
    int level = phase * 8 + slot;
    float r = res.r[level];
    const f2* __restrict__ tb =
        reinterpret_cast<const f2*>(tables) + (size_t)level * HASH_SIZE;
    f2* __restrict__ wl = reinterpret_cast<f2*>(ws) + (size_t)level * N;
    int base = chunk * PTS_PER_BLOCK + threadIdx.x;
#pragma unroll
    for (int i = 0; i < PTS_PER_BLOCK / THREADS; ++i) {
        int n = base + i * THREADS;
        if (n >= N) break;
        float px = __builtin_nontemporal_load(x + 3 * (size_t)n + 0);
        float py = __builtin_nontemporal_load(x + 3 * (size_t)n + 1);
        float pz = __builtin_nontemporal_load(x + 3 * (size_t)n + 2);
        clamp3(px, py, pz);
        f2 a = enc_pl_merged(tb, r, px, py, pz);
        __builtin_nontemporal_store(a, wl + n);
    }
}

__global__ __launch_bounds__(THREADS) void hashenc_transpose_nosort_kernel(
    const float* __restrict__ ws, float* __restrict__ out, int N)
{
    int c    = threadIdx.x & 7;
    int pid  = threadIdx.x >> 3;
    int base = blockIdx.x * 256;
    const f2* __restrict__ w2 = reinterpret_cast<const f2*>(ws);
#pragma unroll
    for (int i = 0; i < 8; ++i) {
        int p = base + i * 32 + pid;
        if (p >= N) return;
        f2 a = __builtin_nontemporal_load(w2 + (size_t)(2 * c)     * N + p);
        f2 b = __builtin_nontemporal_load(w2 + (size_t)(2 * c + 1) * N + p);
        f4 v; v.x = a.x; v.y = a.y; v.z = b.x; v.w = b.y;
        __builtin_nontemporal_store(
            v, reinterpret_cast<f4*>(out + (size_t)p * (2 * NL) + c * 4));
    }
}

__global__ __launch_bounds__(THREADS) void hashenc_mono_kernel(
    const float* __restrict__ x, const float* __restrict__ tables,
    float* __restrict__ out, int N, Res16 res)
{
    int n = blockIdx.x * THREADS + threadIdx.x;
    if (n >= N) return;
    float px = x[3 * (size_t)n + 0], py = x[3 * (size_t)n + 1], pz = x[3 * (size_t)n + 2];
    clamp3(px, py, pz);
    float acc[2 * NL];
#pragma unroll
    for (int l = 0; l < NL; ++l) {
        const f2* tb = reinterpret_cast<const f2*>(tables) + (size_t)l * HASH_SIZE;
        f2 a = enc_pl_merged(tb, res.r[l], px, py, pz);
        acc[2 * l] = a.x; acc[2 * l + 1] = a.y;
    }
    f4* o = reinterpret_cast<f4*>(out + (size_t)n * (2 * NL));
#pragma unroll
    for (int q = 0; q < 8; ++q) {
        f4 v; v.x = acc[4*q]; v.y = acc[4*q+1]; v.z = acc[4*q+2]; v.w = acc[4*q+3];
        o[q] = v;
    }
}

extern "C" void kernel_launch(void* const* d_in, const int* in_sizes, int n_in,
                              void* d_out, int out_size, void* d_ws, size_t ws_size,
                              hipStream_t stream)
{
    const float* x      = (const float*)d_in[0];
    const float* tables = (const float*)d_in[1];
    float* out          = (float*)d_out;
    int N = in_sizes[0] / 3;

    // Replicate numpy's resolutions bit-for-bit with glibc doubles (levels
    // 3/6/9/12/15 sit on exact ceil boundaries -> must compute, not guess).
    Res16 res;
    double b = exp((log(512.0) - log(16.0)) / 15.0);
    for (int i = 0; i < NL; ++i)
        res.r[i] = (float)(int)ceil(16.0 * pow(b, (double)i));

    // ws floats: [ fine enc: NFINE*N*2 | sx: N*4 | perm: N | hist: NB |
    //              cursor: NB | bsum+bpre: 2*SCAN_BLOCKS ]
    size_t enc_f      = (size_t)NFINE * N * 2;
    size_t need_sort  = (enc_f + (size_t)N * 5 + 2 * NB + 2 * SCAN_BLOCKS) * sizeof(float);
    size_t need_plain = (size_t)NL * N * 2 * sizeof(float);

    if (ws_size >= need_sort) {
        float* wse    = (float*)d_ws;
        float* sx     = wse + enc_f;
        int*   perm   = (int*)(sx + (size_t)N * 4);
        int*   hist   = perm + N;
        int*   cursor = hist + NB;
        int*   bsum   = cursor + NB;
        int*   bpre   = bsum + SCAN_BLOCKS;

        hipMemsetAsync(hist, 0, NB * sizeof(int), stream);
        hipLaunchKernelGGL(hist_kernel, dim3(256), dim3(THREADS), 0, stream,
                           x, hist, N);
        hipLaunchKernelGGL(scan1_kernel, dim3(SCAN_BLOCKS), dim3(THREADS), 0, stream,
                           hist, bsum);
        hipLaunchKernelGGL(scan2_kernel, dim3(1), dim3(SCAN_BLOCKS), 0, stream,
                           bsum, bpre);
        hipLaunchKernelGGL(scan3_kernel, dim3(SCAN_BLOCKS), dim3(THREADS), 0, stream,
                           hist, bpre, cursor);
        hipLaunchKernelGGL(scatter_kernel, dim3((N + THREADS - 1) / THREADS),
                           dim3(THREADS), 0, stream, x, cursor, sx, perm, N);

        int nchunks = (N + PTS_PER_BLOCK - 1) / PTS_PER_BLOCK;
        for (int l = 8; l < NL; ++l) {
            hipLaunchKernelGGL(hashenc_fine_kernel, dim3(nchunks), dim3(THREADS),
                               0, stream,
                               sx,
                               (const float*)(tables + (size_t)l * HASH_SIZE * 2),
                               wse + (size_t)(l - 8) * N * 2,
                               N, res.r[l]);
        }
        hipLaunchKernelGGL(hashenc_transpose_fused_kernel, dim3((N + 255) / 256),
                           dim3(THREADS), 0, stream, wse, sx, perm, tables, out,
                           N, res);
    } else if (ws_size >= need_plain) {
        int nchunks = (N + PTS_PER_BLOCK - 1) / PTS_PER_BLOCK;
        hipLaunchKernelGGL(hashenc_level_nosort_kernel, dim3(2 * 8 * nchunks),
                           dim3(THREADS), 0, stream, x, tables, (float*)d_ws,
                           N, nchunks, res);
        hipLaunchKernelGGL(hashenc_transpose_nosort_kernel, dim3((N + 255) / 256),
                           dim3(THREADS), 0, stream, (const float*)d_ws, out, N);
    } else {
        hipLaunchKernelGGL(hashenc_mono_kernel, dim3((N + THREADS - 1) / THREADS),
                           dim3(THREADS), 0, stream, x, tables, out, N, res);
    }
}